// Round 2
// baseline (31023.935 us; speedup 1.0000x reference)
//
#include <hip/hip_runtime.h>
#include <stdint.h>

// Transducer greedy decode, persistent 2-stage pipeline (R6).
// R5 post-mortem: multicast flags saved exactly the 3 removed LLC hops
// (~460ns each) -> contention was nil; the cost is legs x hops. R6 removes
// an entire leg: stage A is merged into C. C already gathers full h for
// Whh.h; it now also computes its 4-row z-slice INLINE with that gather
// (z = tanh(tnp + Wpn.h + bj)), publishes z, then computes gates while L
// computes logits. Wtn.x_t partials for t+1 are prefetched into registers
// during C's slack (gates/FL-wait window) -> never on the critical path.
// Also: red[] scatter writes get a (b+dq)&31 column rotation (4-way -> free
// 2-way bank access; readers apply the same rotation).
// Stages (224 blk x 256 thr, 1 blk/CU):
//   C(160): z-slice + publish FZ + gates(16 rows) + slot-reduce + decode +
//           LSTM elementwise + publish FC. 4 h-rows / 4 z-rows per block.
//   L(64):  16-v logit tile -> per-block argmax/sumexp slots, publish FL.
// Chain: C(t-1) h -> C(t) z -> L(t) logits -> C-tail(t).

typedef unsigned long long u64;
typedef uint32_t u32;

#define TT 1000
#define DD 640
#define GG 2560
#define VV 1024

#define NC 160
#define NL 64
#define NBLK (NC + NL) // 224

// ws layout (float offsets)
static constexpr size_t OFF_WTN  = 0;                      // 640x640  WT4
static constexpr size_t OFF_WPN  = OFF_WTN  + 409600;
static constexpr size_t OFF_WHH  = OFF_WPN  + 409600;      // 2560x640
static constexpr size_t OFF_WOUT = OFF_WHH  + 1638400;     // 1024x640
static constexpr size_t OFF_P    = OFF_WOUT + 655360;      // 1024x2560
static constexpr size_t OFF_XH   = OFF_P    + 2621440;     // h [2 par][32][640]
static constexpr size_t OFF_XZ   = OFF_XH   + 40960;       // z [32][640]
static constexpr size_t OFF_SC   = OFF_XZ   + 20480;       // score[32]
static constexpr size_t OFF_LKEY = OFF_SC   + 32;          // u64 [32][64] slots
static constexpr size_t OFF_LSE  = OFF_LKEY + 4096;        // f32 [32][64] slots
// multicast flags: [consumer][producer] slots, 4 ints (16B) per slot.
// FC: prod = 160 C, cons = 160 C   (h(t) ready)
// FZ: prod = 160 C, cons = 64  L   (z(t) ready)
// FL: prod = 64  L, cons = 160 C   (logits(t) ready)
static constexpr size_t OFF_MCFC = OFF_LSE  + 2048;        // int[160][160][4]
static constexpr size_t OFF_MCFZ = OFF_MCFC + 102400;      // int[64][160][4]
static constexpr size_t OFF_MCFL = OFF_MCFZ + 40960;       // int[160][64][4]
static constexpr size_t OFF_END  = OFF_MCFL + 40960;       // ~23.9 MB

__device__ __forceinline__ float sigf(float x) { return 1.0f / (1.0f + expf(-x)); }

__device__ __forceinline__ u32 ordf(float f) {
  u32 u = __float_as_uint(f);
  return (u & 0x80000000u) ? ~u : (u | 0x80000000u);
}

// ---- coherent (LLC) accesses: bypass L1/L2, no fences (R3/R4-validated) ----
__device__ __forceinline__ void cstore2(float* p, float a, float b) {
  u64 v = ((u64)__float_as_uint(b) << 32) | (u64)__float_as_uint(a);
  __hip_atomic_store((u64*)p, v, __ATOMIC_RELAXED, __HIP_MEMORY_SCOPE_AGENT);
}
__device__ __forceinline__ float2 cload2(const float* p) {
  u64 v = __hip_atomic_load((const u64*)p, __ATOMIC_RELAXED, __HIP_MEMORY_SCOPE_AGENT);
  return make_float2(__uint_as_float((u32)v), __uint_as_float((u32)(v >> 32)));
}
__device__ __forceinline__ u64 cloadu64(const u64* p) {
  return __hip_atomic_load(p, __ATOMIC_RELAXED, __HIP_MEMORY_SCOPE_AGENT);
}
__device__ __forceinline__ void cstoreu64(u64* p, u64 v) {
  __hip_atomic_store(p, v, __ATOMIC_RELAXED, __HIP_MEMORY_SCOPE_AGENT);
}
__device__ __forceinline__ float cloadf(const float* p) {
  return __hip_atomic_load(p, __ATOMIC_RELAXED, __HIP_MEMORY_SCOPE_AGENT);
}
__device__ __forceinline__ void cstoref(float* p, float v) {
  __hip_atomic_store(p, v, __ATOMIC_RELAXED, __HIP_MEMORY_SCOPE_AGENT);
}

// consumer: poll own private slots, one lane per producer.
__device__ __forceinline__ void wait_mc(const int* mc, int nprod, int target) {
  if ((int)threadIdx.x < nprod) {
    while (__hip_atomic_load(mc + threadIdx.x * 4, __ATOMIC_RELAXED,
                             __HIP_MEMORY_SCOPE_AGENT) < target)
      __builtin_amdgcn_s_sleep(2);
  }
  __syncthreads();
}
// producer: barrier drains all waves' vmcnt (stores at LLC), then fan out.
__device__ __forceinline__ void publish_mc(int* mc, int ncons, int nprod,
                                           int myprod, int val) {
  __syncthreads();
  if ((int)threadIdx.x < ncons)
    __hip_atomic_store(mc + ((size_t)threadIdx.x * nprod + myprod) * 4, val,
                       __ATOMIC_RELAXED, __HIP_MEMORY_SCOPE_AGENT);
}

__device__ __forceinline__ void fma4(float& a, const float4 w, const float4 x) {
  a = fmaf(w.x, x.x, fmaf(w.y, x.y, fmaf(w.z, x.z, fmaf(w.w, x.w, a))));
}
__device__ __forceinline__ void fma22(float& a, const float4 w, const float2 xa,
                                      const float2 xb) {
  a = fmaf(w.x, xa.x, fmaf(w.y, xa.y, fmaf(w.z, xb.x, fmaf(w.w, xb.y, a))));
}

// ---- setup kernels ----

// W[j][d] (row-major, K=640) -> WT4: float4 at (d/4)*J + j holds W[j][4q..4q+3]
__global__ __launch_bounds__(256) void k_wt4(const float* __restrict__ W,
                                             float* __restrict__ WT4, int J) {
  __shared__ float tile[64][65];
  int nj = J >> 6;
  int tj = blockIdx.x % nj, tk = blockIdx.x / nj;
  int jb = tj << 6, kb = tk << 6;
  for (int i = threadIdx.x; i < 4096; i += 256) {
    int d = i & 63, j = i >> 6;
    tile[j][d] = W[(size_t)(jb + j) * DD + (kb + d)];
  }
  __syncthreads();
  for (int i = threadIdx.x; i < 1024; i += 256) {
    int j = i & 63, q = i >> 6;
    float4 v = make_float4(tile[j][q * 4], tile[j][q * 4 + 1], tile[j][q * 4 + 2],
                           tile[j][q * 4 + 3]);
    ((float4*)WT4)[(size_t)((kb >> 2) + q) * J + (jb + j)] = v;
  }
}

// P[v][g] = sum_d E[v][d] * Wih[g][d]
__global__ __launch_bounds__(256) void k_pgemm(const float* __restrict__ E,
                                               const float* __restrict__ Wih,
                                               float* __restrict__ P) {
  __shared__ float As[16][65], Bs[16][65];
  int vt = blockIdx.x & 15, gt = blockIdx.x >> 4;
  int vb = vt << 6, gb = gt << 6;
  int tv = threadIdx.x & 15, tg = threadIdx.x >> 4;
  float acc[4][4] = {};
  for (int kb = 0; kb < DD; kb += 16) {
    for (int i = threadIdx.x; i < 1024; i += 256) {
      int k = i & 15, x = i >> 4;
      As[k][x] = E[(size_t)(vb + x) * DD + kb + k];
      Bs[k][x] = Wih[(size_t)(gb + x) * DD + kb + k];
    }
    __syncthreads();
#pragma unroll
    for (int k = 0; k < 16; ++k) {
      float av[4], bv[4];
#pragma unroll
      for (int i = 0; i < 4; ++i) av[i] = As[k][tv * 4 + i];
#pragma unroll
      for (int j = 0; j < 4; ++j) bv[j] = Bs[k][tg * 4 + j];
#pragma unroll
      for (int i = 0; i < 4; ++i)
#pragma unroll
        for (int j = 0; j < 4; ++j) acc[i][j] = fmaf(av[i], bv[j], acc[i][j]);
    }
    __syncthreads();
  }
#pragma unroll
  for (int i = 0; i < 4; ++i)
#pragma unroll
    for (int j = 0; j < 4; ++j)
      P[(size_t)(vb + tv * 4 + i) * GG + gb + tg * 4 + j] = acc[i][j];
}

// initial LSTM step: x0=E[0], h0=c0=0 -> h1 identical for all b; XH parity 0.
// Also zeroes the multicast flag region (plain stores; kernel-boundary flush
// makes them visible before k_decode polls -- R4/R5-validated pattern).
__global__ __launch_bounds__(256) void k_init(float* __restrict__ ws,
                                              const float* __restrict__ bl) {
  const float* P = ws + OFF_P;
  float* XH0 = ws + OFF_XH;
  int tid = blockIdx.x * 256 + threadIdx.x;
  if (tid < DD) {
    int j = tid;
    float gi = P[j] + bl[j];
    float gg = P[1280 + j] + bl[1280 + j];
    float go = P[1920 + j] + bl[1920 + j];
    float c1 = sigf(gi) * tanhf(gg);
    float h1 = sigf(go) * tanhf(c1);
    for (int b = 0; b < 32; ++b) XH0[b * DD + j] = h1;
  }
  int* mc = (int*)(ws + OFF_MCFC);
  for (int i = tid; i < 184320; i += 1024) mc[i] = 0; // 102400+40960+40960
}

// ---- persistent decode ----
__global__ __launch_bounds__(256, 1) void k_decode(float* __restrict__ ws,
                                                   const float* __restrict__ tn,
                                                   const float* __restrict__ bl,
                                                   const float* __restrict__ bj,
                                                   const float* __restrict__ bo,
                                                   float* __restrict__ out) {
  const float* WTN = ws + OFF_WTN;
  const float* WPN = ws + OFF_WPN;
  const float* WHH = ws + OFF_WHH;
  const float* WOUT = ws + OFF_WOUT;
  const float* P = ws + OFF_P;
  float* XH = ws + OFF_XH;
  float* XZ = ws + OFF_XZ;
  float* SCg = ws + OFF_SC;
  u64* LKEY = (u64*)(ws + OFF_LKEY);
  float* LSE = ws + OFF_LSE;
  int* MCFC = (int*)(ws + OFF_MCFC);
  int* MCFZ = (int*)(ws + OFF_MCFZ);
  int* MCFL = (int*)(ws + OFF_MCFL);

  // ~126 KB static LDS: functional + forces 1 block/CU (exclusive residency).
  __shared__ float xbuf[32 * 648];     // C: h stash (16B-aligned rows)
  __shared__ float red[16 * 16 * 33];  // partial sums (rotated columns)
  __shared__ float aux[32 * 33];       // C: z rows then gates; L: logit tile
  __shared__ u64 kred[32 * 9];
  __shared__ float sered[32 * 9];
  __shared__ float c_lds[4 * 33], h_lds[4 * 33];
  __shared__ float sc_lds[32];
  __shared__ int tok_lds[32], nb_lds[32], lt_lds[32];

  const int bid = blockIdx.x, tid = threadIdx.x;
  const int dq = tid >> 4, bp = tid & 15; // 16 d-groups x 16 b-pairs
  const int d0 = dq * 40, b0 = bp * 2;

  if (bid < NC) {
    // ---- stage C: z-slice -> FZ -> gates -> tn-prefetch -> FL -> tail ----
    const int cb = bid, j0 = cb * 4; // 4 h-rows AND 4 z-rows per block
    const int* myFC = MCFC + (size_t)cb * 640; // 160 slots * 4 ints
    const int* myFL = MCFL + (size_t)cb * 256; // 64 slots * 4 ints
    {
      int jj = (tid >> 5) & 3, b = tid & 31, j = j0 + jj;
      if (tid < 128) {
        float gi = P[j] + bl[j];
        float gg = P[1280 + j] + bl[1280 + j];
        float go = P[1920 + j] + bl[1920 + j];
        float c1 = sigf(gi) * tanhf(gg);
        c_lds[jj * 33 + b] = c1;
        h_lds[jj * 33 + b] = sigf(go) * tanhf(c1);
      }
    }
    if (tid < 32) { lt_lds[tid] = 0; sc_lds[tid] = 0.f; }
    // prologue: Wtn.x partials for t=0 (register-resident)
    float acc_tn[4][2];
#pragma unroll
    for (int r = 0; r < 4; ++r) acc_tn[r][0] = acc_tn[r][1] = 0.f;
    {
      const float* t0p = tn + ((size_t)b0 * TT + 0) * DD + d0;
      const float* t1p = t0p + (size_t)TT * DD;
#pragma unroll 5
      for (int q = 0; q < 10; ++q) {
        float4 x0 = *(const float4*)(t0p + q * 4);
        float4 x1 = *(const float4*)(t1p + q * 4);
        const float4* wt = (const float4*)WTN + (size_t)((d0 + q * 4) >> 2) * DD + j0;
#pragma unroll
        for (int r = 0; r < 4; ++r) {
          fma4(acc_tn[r][0], wt[r], x0);
          fma4(acc_tn[r][1], wt[r], x1);
        }
      }
    }
    __syncthreads();
    for (int t = 0; t < TT; ++t) {
      const int par = t & 1;
      wait_mc(myFC, NC, t); // h(t) ready at LLC
      // (1) z-slice: gather h inline (cload2), stash to xbuf, Wpn FMAs.
      {
        float acc[4][2];
#pragma unroll
        for (int r = 0; r < 4; ++r) {
          acc[r][0] = acc_tn[r][0];
          acc[r][1] = acc_tn[r][1];
        }
        const float* h0p = XH + (size_t)par * 20480 + (size_t)b0 * DD + d0;
        const float* h1p = h0p + DD;
#pragma unroll 5
        for (int q = 0; q < 10; ++q) {
          float2 a0 = cload2(h0p + q * 4), a1 = cload2(h0p + q * 4 + 2);
          float2 b1 = cload2(h1p + q * 4), b2 = cload2(h1p + q * 4 + 2);
          *(float4*)&xbuf[b0 * 648 + d0 + q * 4] = make_float4(a0.x, a0.y, a1.x, a1.y);
          *(float4*)&xbuf[(b0 + 1) * 648 + d0 + q * 4] = make_float4(b1.x, b1.y, b2.x, b2.y);
          const float4* wp = (const float4*)WPN + (size_t)((d0 + q * 4) >> 2) * DD + j0;
#pragma unroll
          for (int r = 0; r < 4; ++r) {
            fma22(acc[r][0], wp[r], a0, a1);
            fma22(acc[r][1], wp[r], b1, b2);
          }
        }
#pragma unroll
        for (int r = 0; r < 4; ++r) {
          red[(dq * 4 + r) * 33 + ((b0 + dq) & 31)] = acc[r][0];
          red[(dq * 4 + r) * 33 + ((b0 + 1 + dq) & 31)] = acc[r][1];
        }
      }
      __syncthreads();
      if (tid < 128) {
        int r = tid >> 5, b = tid & 31;
        float s = 0.f;
#pragma unroll
        for (int k = 0; k < 16; ++k) s += red[(k * 4 + r) * 33 + ((b + k) & 31)];
        aux[r * 33 + b] = tanhf(s + bj[j0 + r]);
      }
      __syncthreads();
      if (tid < 64) {
        int jp = tid >> 5, b = tid & 31;
        cstore2(XZ + (size_t)b * DD + j0 + jp * 2, aux[(jp * 2) * 33 + b],
                aux[(jp * 2 + 1) * 33 + b]);
      }
      publish_mc(MCFZ, NL, NC, cb, t + 1); // z(t) ready
      // (2) gates = Whh.h from xbuf (16 rows = 4 gates x 4 j)
      {
        float acc[16][2] = {};
#pragma unroll 5
        for (int q = 0; q < 10; ++q) {
          const int d = d0 + q * 4;
          float4 h0 = *(const float4*)&xbuf[b0 * 648 + d];
          float4 h1 = *(const float4*)&xbuf[(b0 + 1) * 648 + d];
          const float4* w0 = (const float4*)WHH + (size_t)(d >> 2) * GG + j0;
#pragma unroll
          for (int g = 0; g < 4; ++g) {
            const float4* wg = w0 + g * DD;
#pragma unroll
            for (int jj = 0; jj < 4; ++jj) {
              fma4(acc[g * 4 + jj][0], wg[jj], h0);
              fma4(acc[g * 4 + jj][1], wg[jj], h1);
            }
          }
        }
#pragma unroll
        for (int r = 0; r < 16; ++r) {
          red[(dq * 16 + r) * 33 + ((b0 + dq) & 31)] = acc[r][0];
          red[(dq * 16 + r) * 33 + ((b0 + 1 + dq) & 31)] = acc[r][1];
        }
      }
      __syncthreads();
#pragma unroll
      for (int o = tid; o < 512; o += 256) {
        int r16 = o >> 5, b = o & 31;
        float s = 0.f;
#pragma unroll
        for (int k = 0; k < 16; ++k) s += red[(k * 16 + r16) * 33 + ((b + k) & 31)];
        aux[r16 * 33 + b] = s; // gates: row g*4+jj
      }
      // (3) tn-prefetch for t+1 (registers only; fills FL-wait slack)
      if (t + 1 < TT) {
#pragma unroll
        for (int r = 0; r < 4; ++r) acc_tn[r][0] = acc_tn[r][1] = 0.f;
        const float* t0p = tn + ((size_t)b0 * TT + (t + 1)) * DD + d0;
        const float* t1p = t0p + (size_t)TT * DD;
#pragma unroll 5
        for (int q = 0; q < 10; ++q) {
          float4 x0 = *(const float4*)(t0p + q * 4);
          float4 x1 = *(const float4*)(t1p + q * 4);
          const float4* wt = (const float4*)WTN + (size_t)((d0 + q * 4) >> 2) * DD + j0;
#pragma unroll
          for (int r = 0; r < 4; ++r) {
            fma4(acc_tn[r][0], wt[r], x0);
            fma4(acc_tn[r][1], wt[r], x1);
          }
        }
      }
      wait_mc(myFL, NL, t + 1); // logits(t) ready
      // (4) tree-reduce per-block argmax/sumexp slots
      {
        int b = tid >> 3, ch = tid & 7;
        const u64* kp = LKEY + (size_t)b * 64 + ch * 8;
        u64 km = 0;
#pragma unroll
        for (int i = 0; i < 8; ++i) {
          u64 x = cloadu64(kp + i);
          km = x > km ? x : km;
        }
        kred[b * 9 + ch] = km;
        if (cb == 0) {
          const float* sp = LSE + (size_t)b * 64 + ch * 8;
          float ss = 0.f;
#pragma unroll
          for (int i = 0; i < 8; ++i) ss += cloadf(sp + i);
          sered[b * 9 + ch] = ss;
        }
      }
      __syncthreads();
      if (tid < 32) {
        int b = tid;
        u64 km = 0;
#pragma unroll
        for (int ch = 0; ch < 8; ++ch) {
          u64 x = kred[b * 9 + ch];
          km = x > km ? x : km;
        }
        u32 ou = (u32)(km >> 32);
        u32 fb = (ou & 0x80000000u) ? (ou & 0x7FFFFFFFu) : ~ou;
        float m = __uint_as_float(fb);
        int v = (int)(0xFFFFFFFFu - (u32)(km & 0xFFFFFFFFull));
        int nb = (v != 0) ? 1 : 0;
        int tok = nb ? v : lt_lds[b];
        lt_lds[b] = tok;
        tok_lds[b] = tok;
        nb_lds[b] = nb;
        if (cb == 0) {
          float S = 0.f;
#pragma unroll
          for (int ch = 0; ch < 8; ++ch) S += sered[b * 9 + ch];
          float lp = m - logf(S); // logits bounded: no max-shift needed
          if (nb) sc_lds[b] += lp;
          out[(size_t)b * TT + t] = nb ? (float)v : 0.0f;
          if (t == TT - 1) SCg[b] = sc_lds[b];
        }
      }
      __syncthreads();
      if (tid < 128) {
        int jj = tid >> 5, b = tid & 31, j = j0 + jj;
        if (nb_lds[b]) {
          const float* Pr = P + (size_t)tok_lds[b] * GG;
          float gi = aux[(0 + jj) * 33 + b] + Pr[j] + bl[j];
          float gf = aux[(4 + jj) * 33 + b] + Pr[640 + j] + bl[640 + j];
          float gg = aux[(8 + jj) * 33 + b] + Pr[1280 + j] + bl[1280 + j];
          float go = aux[(12 + jj) * 33 + b] + Pr[1920 + j] + bl[1920 + j];
          float c = c_lds[jj * 33 + b];
          float cn = sigf(gf) * c + sigf(gi) * tanhf(gg);
          float hn = sigf(go) * tanhf(cn);
          c_lds[jj * 33 + b] = cn;
          h_lds[jj * 33 + b] = hn;
        }
      }
      __syncthreads();
      if (tid < 64) {
        int jp = tid >> 5, b = tid & 31;
        cstore2(XH + (size_t)(1 - par) * 20480 + (size_t)b * DD + j0 + jp * 2,
                h_lds[(jp * 2) * 33 + b], h_lds[(jp * 2 + 1) * 33 + b]);
      }
      publish_mc(MCFC, NC, NC, cb, t + 1); // h(t+1) ready
    }
  } else {
    // ---- stage L: 16-v logit tile -> per-block slots (zero-RMW) ----
    const int lb = bid - NC, v0 = lb * 16;
    const int* myFZ = MCFZ + (size_t)lb * 640; // 160 slots * 4 ints
    for (int t = 0; t < TT; ++t) {
      wait_mc(myFZ, NC, t + 1); // z(t) ready
      const float* z0p = XZ + (size_t)b0 * DD + d0;
      const float* z1p = z0p + DD;
      float acc[16][2] = {};
#pragma unroll 5
      for (int q = 0; q < 10; ++q) {
        float2 z0a = cload2(z0p + q * 4), z0b = cload2(z0p + q * 4 + 2);
        float2 z1a = cload2(z1p + q * 4), z1b = cload2(z1p + q * 4 + 2);
        const float4* wo = (const float4*)WOUT + (size_t)((d0 + q * 4) >> 2) * VV + v0;
#pragma unroll
        for (int r = 0; r < 16; ++r) {
          float4 w = wo[r];
          fma22(acc[r][0], w, z0a, z0b);
          fma22(acc[r][1], w, z1a, z1b);
        }
      }
#pragma unroll
      for (int r = 0; r < 16; ++r) {
        red[(dq * 16 + r) * 33 + ((b0 + dq) & 31)] = acc[r][0];
        red[(dq * 16 + r) * 33 + ((b0 + 1 + dq) & 31)] = acc[r][1];
      }
      __syncthreads();
#pragma unroll
      for (int o = tid; o < 512; o += 256) {
        int r = o >> 5, b = o & 31;
        float s = bo[v0 + r];
#pragma unroll
        for (int k = 0; k < 16; ++k) s += red[(k * 16 + r) * 33 + ((b + k) & 31)];
        aux[r * 33 + b] = s;
      }
      __syncthreads();
      if (tid < 32) {
        int b = tid;
        float m = -1e30f, se = 0.f;
        int vbest = 0;
#pragma unroll
        for (int r = 0; r < 16; ++r) {
          float x = aux[r * 33 + b];
          se += expf(x);
          if (x > m) { m = x; vbest = r; } // strict > => first occurrence
        }
        u64 key = ((u64)ordf(m) << 32) | (u64)(0xFFFFFFFFu - (u32)(v0 + vbest));
        cstoreu64(&LKEY[(size_t)b * 64 + lb], key);
        cstoref(&LSE[(size_t)b * 64 + lb], se);
      }
      publish_mc(MCFL, NC, NL, lb, t + 1); // logits(t) ready
    }
  }
}

__global__ __launch_bounds__(64) void k_final(const float* __restrict__ ws,
                                              float* __restrict__ out) {
  __shared__ float sh[32];
  int t = threadIdx.x;
  if (t < 32) {
    float s = ws[OFF_SC + t];
    out[32000 + t] = s;
    sh[t] = expf(s);
  }
  __syncthreads();
  if (t == 0) {
    float a = 0.f;
    for (int i = 0; i < 32; ++i) a += sh[i];
    out[32032] = a / 32.0f;
  }
}

extern "C" void kernel_launch(void* const* d_in, const int* in_sizes, int n_in,
                              void* d_out, int out_size, void* d_ws, size_t ws_size,
                              hipStream_t stream) {
  const float* tn = (const float*)d_in[0];
  const float* E = (const float*)d_in[1];
  const float* Wih = (const float*)d_in[2];
  const float* Whh = (const float*)d_in[3];
  const float* bl = (const float*)d_in[4];
  const float* Wtn = (const float*)d_in[5];
  const float* Wpn = (const float*)d_in[6];
  const float* bj = (const float*)d_in[7];
  const float* Wout = (const float*)d_in[8];
  const float* bo = (const float*)d_in[9];
  float* ws = (float*)d_ws;
  float* out = (float*)d_out;

  k_wt4<<<100, 256, 0, stream>>>(Wtn, ws + OFF_WTN, DD);
  k_wt4<<<100, 256, 0, stream>>>(Wpn, ws + OFF_WPN, DD);
  k_wt4<<<400, 256, 0, stream>>>(Whh, ws + OFF_WHH, GG);
  k_wt4<<<160, 256, 0, stream>>>(Wout, ws + OFF_WOUT, VV);
  k_pgemm<<<640, 256, 0, stream>>>(E, Wih, ws + OFF_P);
  k_init<<<4, 256, 0, stream>>>(ws, bl);
  k_decode<<<NBLK, 256, 0, stream>>>(ws, tn, bl, bj, bo, out);
  k_final<<<1, 64, 0, stream>>>(ws, out);
}